// Round 10
// baseline (421.700 us; speedup 1.0000x reference)
//
#include <hip/hip_runtime.h>
#include <math.h>

#define B 2
#define L 2048
#define D 1024
#define H 16
#define DK 64
#define DFF 4096
#define EPS 1e-5f

typedef short short8 __attribute__((ext_vector_type(8)));
typedef short short4v __attribute__((ext_vector_type(4)));
typedef float float4v __attribute__((ext_vector_type(4)));
typedef unsigned int u32;

__device__ inline short f2bf(float f) {
    unsigned u = __builtin_bit_cast(unsigned, f);
    u += 0x7fffu + ((u >> 16) & 1u);  // round-to-nearest-even
    return (short)(u >> 16);
}

__device__ inline float bf2f(short s) {
    unsigned u = ((unsigned)(unsigned short)s) << 16;
    return __builtin_bit_cast(float, u);
}

// async 16B global->LDS (dest = wave-uniform base + lane*16)
#define GLOAD_LDS16(gp, lp)                                                  \
    __builtin_amdgcn_global_load_lds(                                        \
        (const __attribute__((address_space(1))) u32*)(const void*)(gp),     \
        (__attribute__((address_space(3))) u32*)(void*)(lp), 16, 0, 0)

// bijective XCD chunk swizzle for 2D grids with gridDim.y % 8 == 0.
__device__ inline void xcd_remap(int& bx, int& by) {
    const int nbx = gridDim.x, nby = gridDim.y;
    const int orig = blockIdx.x + nbx * blockIdx.y;
    const int k = orig & 7, j = orig >> 3;
    const int nyc = nby >> 3;
    bx = j % nbx;
    by = k * nyc + j / nbx;
}

// ---------------- LayerNorm over (L,D) per batch ----------------------------

__global__ __launch_bounds__(256) void red_partial(const float* __restrict__ X,
                                                   float* __restrict__ part) {
    int b = blockIdx.y;
    const float4* p = (const float4*)(X + (size_t)b * L * D);
    float s = 0.f, ss = 0.f;
    for (int idx = blockIdx.x * 256 + threadIdx.x; idx < L * D / 4; idx += 256 * 256) {
        float4 v = p[idx];
        s += v.x + v.y + v.z + v.w;
        ss += v.x * v.x + v.y * v.y + v.z * v.z + v.w * v.w;
    }
    __shared__ float sh0[256], sh1[256];
    sh0[threadIdx.x] = s; sh1[threadIdx.x] = ss;
    __syncthreads();
    for (int o = 128; o; o >>= 1) {
        if (threadIdx.x < o) {
            sh0[threadIdx.x] += sh0[threadIdx.x + o];
            sh1[threadIdx.x] += sh1[threadIdx.x + o];
        }
        __syncthreads();
    }
    if (threadIdx.x == 0) {
        part[(b * 256 + blockIdx.x) * 2 + 0] = sh0[0];
        part[(b * 256 + blockIdx.x) * 2 + 1] = sh1[0];
    }
}

// npart partials per batch -> stats (mu, rstd)
__global__ __launch_bounds__(256) void red_final(const float* __restrict__ part,
                                                 float* __restrict__ stats,
                                                 int npart) {
    int b = blockIdx.x;
    float s = 0.f, ss = 0.f;
    for (int i = threadIdx.x; i < npart; i += 256) {
        s += part[((size_t)b * npart + i) * 2 + 0];
        ss += part[((size_t)b * npart + i) * 2 + 1];
    }
    __shared__ float sh0[256], sh1[256];
    sh0[threadIdx.x] = s; sh1[threadIdx.x] = ss;
    __syncthreads();
    for (int o = 128; o; o >>= 1) {
        if (threadIdx.x < o) {
            sh0[threadIdx.x] += sh0[threadIdx.x + o];
            sh1[threadIdx.x] += sh1[threadIdx.x + o];
        }
        __syncthreads();
    }
    if (threadIdx.x == 0) {
        const float invN = 1.f / (float)(L * D);
        float mu = sh0[0] * invN;
        float var = sh1[0] * invN - mu * mu;
        stats[b * 2 + 0] = mu;
        stats[b * 2 + 1] = rsqrtf(var + EPS);
    }
}

__global__ __launch_bounds__(256) void ln_apply_bf(const float* __restrict__ X,
                                                   const float* __restrict__ W,
                                                   const float* __restrict__ Bb,
                                                   const float* __restrict__ stats,
                                                   short* __restrict__ Yn) {
    int b = blockIdx.y;
    float mu = stats[b * 2 + 0];
    float rstd = stats[b * 2 + 1];
    size_t e = (size_t)(blockIdx.x * 256 + threadIdx.x) * 4;
    const float4 xv = *(const float4*)(X + (size_t)b * L * D + e);
    const float4 wv = *(const float4*)(W + e);
    const float4 bv = *(const float4*)(Bb + e);
    short4v o;
    o[0] = f2bf((xv.x - mu) * rstd * wv.x + bv.x);
    o[1] = f2bf((xv.y - mu) * rstd * wv.y + bv.y);
    o[2] = f2bf((xv.z - mu) * rstd * wv.z + bv.z);
    o[3] = f2bf((xv.w - mu) * rstd * wv.w + bv.w);
    *(short4v*)(Yn + (size_t)b * L * D + e) = o;
}

__global__ __launch_bounds__(256) void convert_bf(const float* __restrict__ X,
                                                  short* __restrict__ Y) {
    size_t e = (size_t)(blockIdx.x * 256 + threadIdx.x) * 4;
    const float4 v = *(const float4*)(X + e);
    short4v o = {f2bf(v.x), f2bf(v.y), f2bf(v.z), f2bf(v.w)};
    *(short4v*)(Y + e) = o;
}

// all 6 weight transposes in ONE launch. W [K][N] fp32 -> WT [N][K] bf16.
__global__ __launch_bounds__(256) void wt_transpose_all(
        const float* __restrict__ Wq, const float* __restrict__ Wk,
        const float* __restrict__ Wv, const float* __restrict__ Wo,
        const float* __restrict__ W1, const float* __restrict__ W2,
        short* __restrict__ WqT, short* __restrict__ WkvT,
        short* __restrict__ WoT, short* __restrict__ W1T,
        short* __restrict__ W2T) {
    const int id = blockIdx.x;
    const float* W; short* WT; int K, N, rel;
    if (id < 1024)      { W = Wq; WT = WqT;                    K = 1024; N = 1024; rel = id; }
    else if (id < 2048) { W = Wk; WT = WkvT;                   K = 1024; N = 1024; rel = id - 1024; }
    else if (id < 3072) { W = Wv; WT = WkvT + (size_t)D * D;   K = 1024; N = 1024; rel = id - 2048; }
    else if (id < 4096) { W = Wo; WT = WoT;                    K = 1024; N = 1024; rel = id - 3072; }
    else if (id < 8192) { W = W1; WT = W1T;                    K = 1024; N = 4096; rel = id - 4096; }
    else                { W = W2; WT = W2T;                    K = 4096; N = 1024; rel = id - 8192; }
    const int lb = (N == 4096) ? 7 : 5;          // log2(N/32)
    const int bx = rel & ((1 << lb) - 1), by = rel >> lb;

    __shared__ short tile[32][33];
    const int t = threadIdx.x;
    const int tx = t & 31, ty = t >> 5;  // 32 x 8
    const int k0 = by * 32, n0 = bx * 32;
#pragma unroll
    for (int i = 0; i < 4; ++i) {
        const int k = ty + i * 8;
        tile[k][tx] = f2bf(W[(size_t)(k0 + k) * N + n0 + tx]);
    }
    __syncthreads();
#pragma unroll
    for (int i = 0; i < 4; ++i) {
        const int n = ty + i * 8;
        WT[(size_t)(n0 + n) * K + k0 + tx] = tile[tx][n];
    }
}

// ---------------- bf16 MFMA GEMM, counted-vmcnt double-buffer ---------------
// Schedule per K-tile (BK=64): stage(t+1 -> buf^1); vmcnt(8); s_barrier;
// compute(buf); s_barrier. Final iter drains vmcnt(0) once. XOR swizzle both
// sides (measured 0 conflicts, rounds 3/5).

__device__ __forceinline__ void cv128_body(const short* __restrict__ A,
                                           const short* __restrict__ BT,
                                           const float* __restrict__ bias,
                                           const float* __restrict__ Res,
                                           void* __restrict__ Cout,
                                           int N, int Kloop, int lda, int flags,
                                           int m0, int n0,
                                           short* __restrict__ AsB,
                                           short* __restrict__ BsB) {
    const int t = threadIdx.x;
    const int wave = t >> 6, lane = t & 63;
    const int m16 = lane & 15, q4 = lane >> 4;
    const int wm = (wave >> 1) * 64, wn = (wave & 1) * 64;
    const int xorm = m16 & 7;
    const int BUFE = 128 * 64;

    float4v acc[4][4];
#pragma unroll
    for (int i = 0; i < 4; ++i)
#pragma unroll
        for (int j = 0; j < 4; ++j) acc[i][j] = (float4v){0.f, 0.f, 0.f, 0.f};

    auto stage = [&](int buf, int k0) {
        short* AsBuf = AsB + buf * BUFE;
        short* BsBuf = BsB + buf * BUFE;
#pragma unroll
        for (int p = 0; p < 4; ++p) {          // A: 128x64 bf16 = 16 KB
            const int s = p * 256 + t;
            const int row = s >> 3;
            const int col = ((s & 7) ^ (row & 7)) * 8;
            GLOAD_LDS16(A + (size_t)(m0 + row) * lda + k0 + col,
                        AsBuf + (p * 256 + wave * 64) * 8);
        }
#pragma unroll
        for (int p = 0; p < 4; ++p) {          // B: 128x64 bf16 = 16 KB
            const int s = p * 256 + t;
            const int row = s >> 3;
            const int col = ((s & 7) ^ (row & 7)) * 8;
            GLOAD_LDS16(BT + (size_t)(n0 + row) * lda + k0 + col,
                        BsBuf + (p * 256 + wave * 64) * 8);
        }
    };

    auto compute = [&](int buf) {
        const short* AsBuf = AsB + buf * BUFE;
        const short* BsBuf = BsB + buf * BUFE;
#pragma unroll
        for (int kk = 0; kk < 2; ++kk) {
            const int slot = ((kk * 4 + q4) ^ xorm) * 8;
            short8 af[4], bf[4];
#pragma unroll
            for (int mi = 0; mi < 4; ++mi)
                af[mi] = *(const short8*)&AsBuf[(wm + mi * 16 + m16) * 64 + slot];
#pragma unroll
            for (int ni = 0; ni < 4; ++ni)
                bf[ni] = *(const short8*)&BsBuf[(wn + ni * 16 + m16) * 64 + slot];
#pragma unroll
            for (int mi = 0; mi < 4; ++mi)
#pragma unroll
                for (int ni = 0; ni < 4; ++ni)
                    acc[mi][ni] = __builtin_amdgcn_mfma_f32_16x16x32_bf16(
                        af[mi], bf[ni], acc[mi][ni], 0, 0, 0);
        }
    };

    const int nt = Kloop >> 6;
    stage(0, 0);
    for (int ti = 0; ti < nt; ++ti) {
        const int cur = ti & 1;
        if (ti + 1 < nt) {
            stage(cur ^ 1, (ti + 1) << 6);
            asm volatile("s_waitcnt vmcnt(8)" ::: "memory");
        } else {
            asm volatile("s_waitcnt vmcnt(0)" ::: "memory");
        }
        __builtin_amdgcn_s_barrier();
        __builtin_amdgcn_sched_barrier(0);
        compute(cur);
        __builtin_amdgcn_s_barrier();
    }

#pragma unroll
    for (int mi = 0; mi < 4; ++mi)
#pragma unroll
        for (int ni = 0; ni < 4; ++ni) {
            const int col = n0 + wn + ni * 16 + m16;
            const float bb = bias ? bias[col] : 0.f;
#pragma unroll
            for (int r = 0; r < 4; ++r) {
                const int row = m0 + wm + mi * 16 + q4 * 4 + r;
                float v = acc[mi][ni][r] + bb;
                if (Res) v += Res[(size_t)row * N + col];
                if (flags & 1) v = fmaxf(v, 0.f);
                if (flags & 2)
                    ((short*)Cout)[(size_t)row * N + col] = f2bf(v);
                else
                    ((float*)Cout)[(size_t)row * N + col] = v;
            }
        }
}

// merged Q + KV projections: 768 blocks (3/CU).
__global__ __launch_bounds__(256) void gemm_qkv(const short* __restrict__ xb,
                                                const short* __restrict__ WqT,
                                                const float* __restrict__ bq,
                                                short* __restrict__ qb,
                                                const short* __restrict__ ynb,
                                                const short* __restrict__ WkvT,
                                                const float* __restrict__ bkv,
                                                short* __restrict__ kvb) {
    __shared__ short As[2][128 * 64];
    __shared__ short Bs[2][128 * 64];
    const int id = blockIdx.x;
    const int k = id & 7, j = id >> 3;       // 768 = 8 * 96
    const int lin = k * 96 + j;              // bijective; XCD k owns [k*96,k*96+96)
    if (lin < 256) {
        const int bx = lin & 7, by = lin >> 3;
        cv128_body(xb, WqT, bq, nullptr, qb, 1024, 1024, 1024, 2,
                   by * 128, bx * 128, &As[0][0], &Bs[0][0]);
    } else {
        const int l2 = lin - 256;
        const int bx = l2 & 15, by = l2 >> 4;
        cv128_body(ynb, WkvT, bkv, nullptr, kvb, 2048, 1024, 1024, 2,
                   by * 128, bx * 128, &As[0][0], &Bs[0][0]);
    }
}

// split-K=2 (Wo: K=1024, W2: K=4096): 512 blocks (2/CU), fp32 partials.
__global__ __launch_bounds__(256) void gemm_cv128_sk(const short* __restrict__ A,
                                                     const short* __restrict__ BT,
                                                     float* __restrict__ part,
                                                     int M, int N, int K) {
    __shared__ short As[2][128 * 64];
    __shared__ short Bs[2][128 * 64];
    const int id = blockIdx.x;
    const int k = id & 7, j = id >> 3;       // 512 = 8 * 64
    const int lin = k * 64 + j;
    const int ks = lin >> 8;                 // XCDs 0-3 -> ks 0, 4-7 -> ks 1
    const int rem = lin & 255;
    const int by = rem & 31, bx = (rem >> 5) & 7;
    const int Kc = K >> 1;
    cv128_body(A + ks * Kc, BT + ks * Kc, nullptr, nullptr,
               part + (size_t)ks * M * N, N, Kc, K, 0,
               by * 128, bx * 128, &As[0][0], &Bs[0][0]);
}

// out = part0 + part1 + bias + Res  (fp32). Final W2 epilogue.
__global__ __launch_bounds__(256) void sk_reduce(const float* __restrict__ part,
                                                 const float* __restrict__ bias,
                                                 const float* __restrict__ Res,
                                                 float* __restrict__ out,
                                                 int MN, int N) {
    const size_t e = (size_t)(blockIdx.x * 256 + threadIdx.x) * 4;
    const float4 p0 = *(const float4*)(part + e);
    const float4 p1 = *(const float4*)(part + (size_t)MN + e);
    const float4 rv = *(const float4*)(Res + e);
    const float4 bv = *(const float4*)(bias + (e & (size_t)(N - 1)));
    float4 o;
    o.x = p0.x + p1.x + rv.x + bv.x;
    o.y = p0.y + p1.y + rv.y + bv.y;
    o.z = p0.z + p1.z + rv.z + bv.z;
    o.w = p0.w + p1.w + rv.w + bv.w;
    *(float4*)(out + e) = o;
}

// Wo epilogue fused with LN2 partial reduction: writes y1 AND per-block
// (sum, sumsq) partials. Grid (2048, B): block covers 1024 consecutive
// elements of batch b (one full D row chunk -> bias col = t*4).
__global__ __launch_bounds__(256) void sk_reduce_ln(const float* __restrict__ part,
                                                    const float* __restrict__ bias,
                                                    const float* __restrict__ Res,
                                                    float* __restrict__ out,
                                                    float* __restrict__ lnpart,
                                                    int MN) {
    const int b = blockIdx.y;
    const size_t e = ((size_t)b * 2048 + blockIdx.x) * 1024 + threadIdx.x * 4;
    const float4 p0 = *(const float4*)(part + e);
    const float4 p1 = *(const float4*)(part + (size_t)MN + e);
    const float4 rv = *(const float4*)(Res + e);
    const float4 bv = *(const float4*)(bias + threadIdx.x * 4);
    float4 o;
    o.x = p0.x + p1.x + rv.x + bv.x;
    o.y = p0.y + p1.y + rv.y + bv.y;
    o.z = p0.z + p1.z + rv.z + bv.z;
    o.w = p0.w + p1.w + rv.w + bv.w;
    *(float4*)(out + e) = o;
    float s = o.x + o.y + o.z + o.w;
    float ss = o.x * o.x + o.y * o.y + o.z * o.z + o.w * o.w;
    __shared__ float sh0[256], sh1[256];
    sh0[threadIdx.x] = s; sh1[threadIdx.x] = ss;
    __syncthreads();
    for (int off = 128; off; off >>= 1) {
        if (threadIdx.x < off) {
            sh0[threadIdx.x] += sh0[threadIdx.x + off];
            sh1[threadIdx.x] += sh1[threadIdx.x + off];
        }
        __syncthreads();
    }
    if (threadIdx.x == 0) {
        lnpart[((size_t)b * 2048 + blockIdx.x) * 2 + 0] = sh0[0];
        lnpart[((size_t)b * 2048 + blockIdx.x) * 2 + 1] = sh1[0];
    }
}

// 256x256 tile, 8 waves (2M x 4N), wave tile 128x64 (W1).
__global__ __launch_bounds__(512) void gemm_cv256(const short* __restrict__ A,
                                                  const short* __restrict__ BT,
                                                  const float* __restrict__ bias,
                                                  const float* __restrict__ Res,
                                                  void* __restrict__ Cout,
                                                  int M, int N, int K, int flags) {
    __shared__ short As[2][256 * 64];
    __shared__ short Bs[2][256 * 64];
    const int t = threadIdx.x;
    const int wave = t >> 6, lane = t & 63;
    const int m16 = lane & 15, q4 = lane >> 4;
    int bx, by;
    xcd_remap(bx, by);
    const int m0 = by * 256, n0 = bx * 256;
    const int wm = (wave >> 2) * 128, wn = (wave & 3) * 64;
    const int xorm = m16 & 7;

    float4v acc[8][4];
#pragma unroll
    for (int i = 0; i < 8; ++i)
#pragma unroll
        for (int j = 0; j < 4; ++j) acc[i][j] = (float4v){0.f, 0.f, 0.f, 0.f};

    auto stage = [&](int buf, int k0) {
#pragma unroll
        for (int p = 0; p < 4; ++p) {          // A: 256x64 bf16 = 32 KB
            const int s = p * 512 + t;
            const int row = s >> 3;
            const int col = ((s & 7) ^ (row & 7)) * 8;
            short* lds = &As[buf][(p * 512 + wave * 64) * 8];
            GLOAD_LDS16(A + (size_t)(m0 + row) * K + k0 + col, lds);
        }
#pragma unroll
        for (int p = 0; p < 4; ++p) {          // B: 256x64 bf16 = 32 KB
            const int s = p * 512 + t;
            const int row = s >> 3;
            const int col = ((s & 7) ^ (row & 7)) * 8;
            short* lds = &Bs[buf][(p * 512 + wave * 64) * 8];
            GLOAD_LDS16(BT + (size_t)(n0 + row) * K + k0 + col, lds);
        }
    };

    auto compute = [&](int buf) {
#pragma unroll
        for (int kk = 0; kk < 2; ++kk) {
            const int slot = ((kk * 4 + q4) ^ xorm) * 8;
            short8 af[8], bf[4];
#pragma unroll
            for (int mi = 0; mi < 8; ++mi)
                af[mi] = *(const short8*)&As[buf][(wm + mi * 16 + m16) * 64 + slot];
#pragma unroll
            for (int ni = 0; ni < 4; ++ni)
                bf[ni] = *(const short8*)&Bs[buf][(wn + ni * 16 + m16) * 64 + slot];
#pragma unroll
            for (int mi = 0; mi < 8; ++mi)
#pragma unroll
                for (int ni = 0; ni < 4; ++ni)
                    acc[mi][ni] = __builtin_amdgcn_mfma_f32_16x16x32_bf16(
                        af[mi], bf[ni], acc[mi][ni], 0, 0, 0);
        }
    };

    const int nt = K >> 6;
    stage(0, 0);
    for (int ti = 0; ti < nt; ++ti) {
        const int cur = ti & 1;
        if (ti + 1 < nt) {
            stage(cur ^ 1, (ti + 1) << 6);
            asm volatile("s_waitcnt vmcnt(8)" ::: "memory");
        } else {
            asm volatile("s_waitcnt vmcnt(0)" ::: "memory");
        }
        __builtin_amdgcn_s_barrier();
        __builtin_amdgcn_sched_barrier(0);
        compute(cur);
        __builtin_amdgcn_s_barrier();
    }

#pragma unroll
    for (int mi = 0; mi < 8; ++mi)
#pragma unroll
        for (int ni = 0; ni < 4; ++ni) {
            const int col = n0 + wn + ni * 16 + m16;
            const float bb = bias[col];
#pragma unroll
            for (int r = 0; r < 4; ++r) {
                const int row = m0 + wm + mi * 16 + q4 * 4 + r;
                float v = acc[mi][ni][r] + bb;
                if (Res) v += Res[(size_t)row * N + col];
                if (flags & 1) v = fmaxf(v, 0.f);
                if (flags & 2)
                    ((short*)Cout)[(size_t)row * N + col] = f2bf(v);
                else
                    ((float*)Cout)[(size_t)row * N + col] = v;
            }
        }
}

// ---------------- V transpose + tile sums (fused) ---------------------------
// tril-ZERO semantics: p=exp(0)=1 for all j>i, so
//   out[i] = (sum_{j<=i} e^{s_j} v_j + sum_{j>i} v_j) / (sum_{j<=i} e^{s_j} + (L-1-i))
// vtb[bh][d][j] = V[b][j][h*64+d] once per (b,h); per-tile column sums fall
// out of the same LDS tile (XOR swizzle permutes within a row -> row-sum ok).
// vtb ALIASES hb[0:8MB] (dead until W1; W1 runs after attention completes).

#define ASTR 72
#define SKV (2 * D)

__global__ __launch_bounds__(256) void v_transpose(const short* __restrict__ KVg,
                                                   short* __restrict__ VT,
                                                   float* __restrict__ Vtile) {
    __shared__ short tile[64 * ASTR];
    __shared__ float sh[4][64];
    const int t = threadIdx.x;
    const int bh = blockIdx.x >> 5;          // 32 j-tiles of 64 per bh
    const int jt = blockIdx.x & 31;
    const int b = bh >> 4, h = bh & (H - 1);
    const size_t baseV = (size_t)b * L * SKV + (size_t)h * DK + D;
    const int j0 = jt * 64;
    const int sj = t >> 3, sd8 = (t & 7) * 8, sm = t & 7;
#pragma unroll
    for (int rep = 0; rep < 2; ++rep) {
        const int j = rep * 32 + sj;
        const short8 vv = *(const short8*)(KVg + baseV + (size_t)(j0 + j) * SKV + sd8);
        const int jsw = ((((j >> 3) ^ sm) << 3) | (j & 7));
#pragma unroll
        for (int i = 0; i < 8; ++i) tile[(sd8 + i) * ASTR + jsw] = vv[i];
    }
    __syncthreads();
#pragma unroll
    for (int rep = 0; rep < 2; ++rep) {
        const int s = rep * 256 + t;
        const int d = s >> 3, c = s & 7;
        const short8 vv = *(const short8*)&tile[d * ASTR + ((c ^ (d >> 3)) << 3)];
        *(short8*)(VT + ((size_t)bh * DK + d) * L + j0 + c * 8) = vv;
    }
    // fused tile sum over j (row d holds a permutation of its j's)
    {
        const int d = t & 63, g = t >> 6;
        float s = 0.f;
#pragma unroll
        for (int c = 0; c < 16; ++c) s += bf2f(tile[d * ASTR + g * 16 + c]);
        sh[g][d] = s;
        __syncthreads();
        if (t < 64)
            Vtile[((size_t)bh * 32 + jt) * 64 + t] =
                sh[0][t] + sh[1][t] + sh[2][t] + sh[3][t];
    }
}

// ---------------- MFMA flash attention v5 (round-8 proven core) -------------
// UNIFORM paired blocks (qt=u then 31-u: 33 tiles/block). Pure global_load_lds
// staging (K from kvb, V^T from vtb) with source-XOR swizzle; 2-deep counted
// vmcnt schedule. V-suffix computed inline in the epilogue from Vtile.

__global__ __launch_bounds__(256) void attn_mfma(const short* __restrict__ Qg,
                                                 const short* __restrict__ KVg,
                                                 const short* __restrict__ VTg,
                                                 const float* __restrict__ Vtile,
                                                 short* __restrict__ O) {
    __shared__ alignas(16) short Kb[2][64 * 64];  // Kb[buf][j][d], XOR-swz
    __shared__ alignas(16) short Vt[2][64 * 64];  // Vt[buf][d][j], XOR-swz
    __shared__ alignas(16) short Pb[64 * ASTR];   // Pb[i][j], swizzled

    const int t = threadIdx.x;
    const int wave = t >> 6;
    const int lane = t & 63;
    const int m16 = lane & 15;
    const int q4 = lane >> 4;

    const int u = blockIdx.x & 15;          // pair id: qt = u, then 31-u
    const int bh = blockIdx.x >> 4;
    const int h = bh & (H - 1);
    const int b = bh >> 4;
    const size_t baseQ = (size_t)b * L * D + (size_t)h * DK;
    const size_t baseK = (size_t)b * L * SKV + (size_t)h * DK;
    const size_t baseVT = (size_t)bh * DK * L;  // vtb [d][j], row stride L

    const int irow = wave * 16 + m16;   // local q row (A-frag row for PV)
    const int ig = irow >> 3;
    const int xorm = m16 & 7;

    auto stage = [&](int buf, int kt0) {
#pragma unroll
        for (int rep = 0; rep < 2; ++rep) {   // K tile: 64 j x 64 d = 8 KB
            const int s = rep * 256 + t;
            const int j = s >> 3;
            const int c = (s & 7) ^ (j & 7);
            GLOAD_LDS16(KVg + baseK + (size_t)(kt0 + j) * SKV + c * 8,
                        &Kb[buf][(rep * 256 + wave * 64) * 8]);
        }
#pragma unroll
        for (int rep = 0; rep < 2; ++rep) {   // V^T tile: 64 d x 64 j = 8 KB
            const int s = rep * 256 + t;
            const int d = s >> 3;
            const int c = (s & 7) ^ (d & 7);
            GLOAD_LDS16(VTg + baseVT + (size_t)d * L + kt0 + c * 8,
                        &Vt[buf][(rep * 256 + wave * 64) * 8]);
        }
    };

#pragma unroll
    for (int pq = 0; pq < 2; ++pq) {
        const int qt = pq ? (31 - u) : u;
        const int q0 = qt * 64;
        const int rowA = q0 + wave * 16 + m16;

        short8 qf[2];
#pragma unroll
        for (int kc = 0; kc < 2; ++kc)
            qf[kc] = *(const short8*)(Qg + baseQ + (size_t)rowA * D + kc * 32 + q4 * 8);

        float lsum = 0.f;
        float4v acc[4];
#pragma unroll
        for (int f = 0; f < 4; ++f) acc[f] = (float4v){0.f, 0.f, 0.f, 0.f};

        stage(0, 0);
        for (int kt = 0; kt <= qt; ++kt) {
            const int cur = kt & 1;
            if (kt < qt) {
                stage(cur ^ 1, (kt + 1) * 64);
                asm volatile("s_waitcnt vmcnt(4)" ::: "memory");
            } else {
                asm volatile("s_waitcnt vmcnt(0)" ::: "memory");
            }
            __builtin_amdgcn_s_barrier();
            __builtin_amdgcn_sched_barrier(0);

            const short* KbC = &Kb[cur][0];
            const short* VtC = &Vt[cur][0];
            const bool diag = (kt == qt);

            // S^T block per f: rows k = f*16 + q4*4 + r, col q = m16
#pragma unroll
            for (int f = 0; f < 4; ++f) {
                const int krow = f * 16 + m16;
                const short8 kf0 = *(const short8*)&KbC[krow * 64 + ((q4 ^ xorm) << 3)];
                const short8 kf1 = *(const short8*)&KbC[krow * 64 + (((4 + q4) ^ xorm) << 3)];
                float4v sv = {0.f, 0.f, 0.f, 0.f};
                sv = __builtin_amdgcn_mfma_f32_16x16x32_bf16(kf0, qf[0], sv, 0, 0, 0);
                sv = __builtin_amdgcn_mfma_f32_16x16x32_bf16(kf1, qf[1], sv, 0, 0, 0);

                float pv[4];
                if (diag) {
#pragma unroll
                    for (int r = 0; r < 4; ++r) {
                        const int jl = f * 16 + q4 * 4 + r;
                        pv[r] = (jl <= irow) ? __expf(sv[r] * 0.125f) : 1.0f;
                    }
                } else {
#pragma unroll
                    for (int r = 0; r < 4; ++r) pv[r] = __expf(sv[r] * 0.125f);
                }
                lsum += pv[0] + pv[1] + pv[2] + pv[3];

                // 4 consecutive k -> one b64 write into swizzled Pb[i][j]
                short4v s4;
                s4[0] = f2bf(pv[0]); s4[1] = f2bf(pv[1]);
                s4[2] = f2bf(pv[2]); s4[3] = f2bf(pv[3]);
                const int jb = f * 2 + (q4 >> 1);
                *(short4v*)&Pb[irow * ASTR + (((jb ^ ig) << 3) | ((q4 & 1) << 2))] = s4;
            }

            // PV (per-wave band of Pb, no extra barrier)
#pragma unroll
            for (int kc = 0; kc < 2; ++kc) {
                const short8 pf = *(const short8*)&Pb[irow * ASTR + (((kc * 4 + q4) ^ ig) << 3)];
#pragma unroll
                for (int f = 0; f < 4; ++f) {
                    const int d = f * 16 + m16;
                    const short8 vf = *(const short8*)&VtC[d * 64 + (((kc * 4 + q4) ^ xorm) << 3)];
                    acc[f] = __builtin_amdgcn_mfma_f32_16x16x32_bf16(pf, vf, acc[f], 0, 0, 0);
                }
            }
            __builtin_amdgcn_s_barrier();
        }

        // denom: reduce lsum over q4 axis, add masked count, broadcast per row
        float s = lsum;
        s += __shfl_xor(s, 16);
        s += __shfl_xor(s, 32);
        s += (float)(L - (qt + 1) * 64);
        const float inv = 1.0f / s;
        float invr[4];
#pragma unroll
        for (int r = 0; r < 4; ++r) invr[r] = __shfl(inv, q4 * 4 + r);

        // masked-tail V suffix, inline from Vtile (L2-hot, once per q-tile)
        const float* vt = Vtile + (size_t)bh * 32 * 64;
#pragma unroll
        for (int f = 0; f < 4; ++f) {
            const int d = f * 16 + m16;
            float vadd = 0.f;
            for (int kt2 = qt + 1; kt2 < 32; ++kt2) vadd += vt[kt2 * 64 + d];
#pragma unroll
            for (int r = 0; r < 4; ++r) {
                const int i = q0 + wave * 16 + q4 * 4 + r;
                O[baseQ + (size_t)i * D + d] = f2bf((acc[f][r] + vadd) * invr[r]);
            }
        }
    }
}

// ---------------- launch ----------------------------------------------------

extern "C" void kernel_launch(void* const* d_in, const int* in_sizes, int n_in,
                              void* d_out, int out_size, void* d_ws, size_t ws_size,
                              hipStream_t stream) {
    const float* x    = (const float*)d_in[0];
    const float* y    = (const float*)d_in[1];
    const float* Wq   = (const float*)d_in[2];
    const float* bq   = (const float*)d_in[3];
    const float* Wk   = (const float*)d_in[4];
    const float* bk   = (const float*)d_in[5];
    const float* Wv   = (const float*)d_in[6];
    const float* bv   = (const float*)d_in[7];
    const float* Wo   = (const float*)d_in[8];
    const float* bo   = (const float*)d_in[9];
    const float* W1   = (const float*)d_in[10];
    const float* b1   = (const float*)d_in[11];
    const float* W2   = (const float*)d_in[12];
    const float* b2   = (const float*)d_in[13];
    const float* ln1w = (const float*)d_in[14];
    const float* ln1b = (const float*)d_in[15];
    const float* ln2w = (const float*)d_in[16];
    const float* ln2b = (const float*)d_in[17];
    float* out = (float*)d_out;

    const size_t F = (size_t)B * L * D;      // 4,194,304
    char* p = (char*)d_ws;
    short* xb    = (short*)p; p += F * 2;
    short* ynb   = (short*)p; p += F * 2;
    short* qb    = (short*)p; p += F * 2;
    short* kvb   = (short*)p; p += 2 * F * 2;     // [M][2048]: k | v
    short* aob   = (short*)p; p += F * 2;
    short* y1nb  = (short*)p; p += F * 2;
    short* hb    = (short*)p; p += (size_t)B * L * DFF * 2;
    float* y1    = (float*)p; p += F * 4;
    short* WqT   = (short*)p; p += (size_t)D * D * 2;
    short* WkvT  = (short*)p; p += (size_t)D * 2 * D * 2;  // [2048][1024]
    short* WoT   = (short*)p; p += (size_t)D * D * 2;
    short* W1T   = (short*)p; p += (size_t)D * DFF * 2;
    short* W2T   = (short*)p; p += (size_t)D * DFF * 2;
    float* biaskv= (float*)p; p += 2 * D * 4;
    float* vtile = (float*)p; p += (size_t)B * H * 32 * DK * 4;
    float* part  = (float*)p; p += (size_t)B * 2048 * 2 * 4;
    float* stats = (float*)p;

    // vtb (V^T, 8 MB) aliases hb[0:8MB]: hb dead until W1 (runs post-attn).
    short* vtb = hb;
    // Wo split-K partials (32 MB) also live in hb (vtb consumed... no:
    // vtb is read by attn; skpartWo written by gemm_cv128_sk AFTER attn done.
    float* skpartWo = (float*)hb;
    // W2 split-K partials reuse dead qb|kvb|aob (32 MB contiguous).
    float* skpart = (float*)qb;

    const int M = B * L;  // 4096

    // all weight transposes in one launch
    wt_transpose_all<<<dim3(12288), 256, 0, stream>>>(Wq, Wk, Wv, Wo, W1, W2,
                                                      WqT, WkvT, WoT, W1T, W2T);
    hipMemcpyAsync(biaskv,     bk, D * sizeof(float), hipMemcpyDeviceToDevice, stream);
    hipMemcpyAsync(biaskv + D, bv, D * sizeof(float), hipMemcpyDeviceToDevice, stream);

    // x -> bf16
    convert_bf<<<dim3(F / 1024), 256, 0, stream>>>(x, xb);

    // LN1(y) -> ynb (bf16)
    red_partial<<<dim3(256, B), 256, 0, stream>>>(y, part);
    red_final<<<dim3(B), 256, 0, stream>>>(part, stats, 256);
    ln_apply_bf<<<dim3(L * D / 1024, B), 256, 0, stream>>>(y, ln1w, ln1b, stats, ynb);

    // q = x@Wq and kv = ynb@[Wk|Wv], merged: 768 blocks = 3/CU
    gemm_qkv<<<dim3(768), 256, 0, stream>>>(xb, WqT, bq, qb, ynb, WkvT, biaskv, kvb);

    // V^T + tile sums (fused, once)
    v_transpose<<<dim3(B * H * 32), 256, 0, stream>>>(kvb, vtb, vtile);

    // attention -> aob (bf16): uniform paired blocks, gload_lds staging;
    // V-suffix computed inline in epilogue from vtile
    attn_mfma<<<dim3(B * H * 16), 256, 0, stream>>>(qb, kvb, vtb, vtile, aob);

    // y1 = y + attn@Wo + bo (fp32): split-K=2 + reduce FUSED with LN2 partials
    gemm_cv128_sk<<<dim3(512), 256, 0, stream>>>(aob, WoT, skpartWo, M, D, D);
    sk_reduce_ln<<<dim3(2048, B), 256, 0, stream>>>(skpartWo, bo, y, y1, part, M * D);
    red_final<<<dim3(B), 256, 0, stream>>>(part, stats, 2048);
    ln_apply_bf<<<dim3(L * D / 1024, B), 256, 0, stream>>>(y1, ln2w, ln2b, stats, y1nb);

    // h = relu(y1n@W1 + b1) (bf16) -- 256^2 8-wave counted-vmcnt kernel
    // (first write to hb; clobbers vtb / Wo partials, both consumed)
    gemm_cv256<<<dim3(DFF / 256, M / 256), 512, 0, stream>>>(y1nb, W1T, b1, nullptr, hb, M, DFF, D, 3);

    // out = y1 + h@W2 + b2 (fp32): split-K=2 partials + fused reduce
    gemm_cv128_sk<<<dim3(512), 256, 0, stream>>>(hb, W2T, skpart, M, D, DFF);
    sk_reduce<<<dim3(M * D / 1024), 256, 0, stream>>>(skpart, b2, y1, out, M * D, D);
}

// Round 11
// 404.930 us; speedup vs baseline: 1.0414x; 1.0414x over previous
//
#include <hip/hip_runtime.h>
#include <math.h>

#define B 2
#define L 2048
#define D 1024
#define H 16
#define DK 64
#define DFF 4096
#define EPS 1e-5f

typedef short short8 __attribute__((ext_vector_type(8)));
typedef short short4v __attribute__((ext_vector_type(4)));
typedef float float4v __attribute__((ext_vector_type(4)));
typedef unsigned int u32;

__device__ inline short f2bf(float f) {
    unsigned u = __builtin_bit_cast(unsigned, f);
    u += 0x7fffu + ((u >> 16) & 1u);  // round-to-nearest-even
    return (short)(u >> 16);
}

__device__ inline float bf2f(short s) {
    unsigned u = ((unsigned)(unsigned short)s) << 16;
    return __builtin_bit_cast(float, u);
}

// async 16B global->LDS (dest = wave-uniform base + lane*16)
#define GLOAD_LDS16(gp, lp)                                                  \
    __builtin_amdgcn_global_load_lds(                                        \
        (const __attribute__((address_space(1))) u32*)(const void*)(gp),     \
        (__attribute__((address_space(3))) u32*)(void*)(lp), 16, 0, 0)

// bijective XCD chunk swizzle for 2D grids with gridDim.y % 8 == 0.
__device__ inline void xcd_remap(int& bx, int& by) {
    const int nbx = gridDim.x, nby = gridDim.y;
    const int orig = blockIdx.x + nbx * blockIdx.y;
    const int k = orig & 7, j = orig >> 3;
    const int nyc = nby >> 3;
    bx = j % nbx;
    by = k * nyc + j / nbx;
}

// ---------------- LayerNorm over (L,D) per batch ----------------------------

__global__ __launch_bounds__(256) void red_partial(const float* __restrict__ X,
                                                   float* __restrict__ part) {
    int b = blockIdx.y;
    const float4* p = (const float4*)(X + (size_t)b * L * D);
    float s = 0.f, ss = 0.f;
    for (int idx = blockIdx.x * 256 + threadIdx.x; idx < L * D / 4; idx += 256 * 256) {
        float4 v = p[idx];
        s += v.x + v.y + v.z + v.w;
        ss += v.x * v.x + v.y * v.y + v.z * v.z + v.w * v.w;
    }
    __shared__ float sh0[256], sh1[256];
    sh0[threadIdx.x] = s; sh1[threadIdx.x] = ss;
    __syncthreads();
    for (int o = 128; o; o >>= 1) {
        if (threadIdx.x < o) {
            sh0[threadIdx.x] += sh0[threadIdx.x + o];
            sh1[threadIdx.x] += sh1[threadIdx.x + o];
        }
        __syncthreads();
    }
    if (threadIdx.x == 0) {
        part[(b * 256 + blockIdx.x) * 2 + 0] = sh0[0];
        part[(b * 256 + blockIdx.x) * 2 + 1] = sh1[0];
    }
}

// npart partials per batch -> stats (mu, rstd)
__global__ __launch_bounds__(256) void red_final(const float* __restrict__ part,
                                                 float* __restrict__ stats,
                                                 int npart) {
    int b = blockIdx.x;
    float s = 0.f, ss = 0.f;
    for (int i = threadIdx.x; i < npart; i += 256) {
        s += part[((size_t)b * npart + i) * 2 + 0];
        ss += part[((size_t)b * npart + i) * 2 + 1];
    }
    __shared__ float sh0[256], sh1[256];
    sh0[threadIdx.x] = s; sh1[threadIdx.x] = ss;
    __syncthreads();
    for (int o = 128; o; o >>= 1) {
        if (threadIdx.x < o) {
            sh0[threadIdx.x] += sh0[threadIdx.x + o];
            sh1[threadIdx.x] += sh1[threadIdx.x + o];
        }
        __syncthreads();
    }
    if (threadIdx.x == 0) {
        const float invN = 1.f / (float)(L * D);
        float mu = sh0[0] * invN;
        float var = sh1[0] * invN - mu * mu;
        stats[b * 2 + 0] = mu;
        stats[b * 2 + 1] = rsqrtf(var + EPS);
    }
}

__global__ __launch_bounds__(256) void ln_apply_bf(const float* __restrict__ X,
                                                   const float* __restrict__ W,
                                                   const float* __restrict__ Bb,
                                                   const float* __restrict__ stats,
                                                   short* __restrict__ Yn) {
    int b = blockIdx.y;
    float mu = stats[b * 2 + 0];
    float rstd = stats[b * 2 + 1];
    size_t e = (size_t)(blockIdx.x * 256 + threadIdx.x) * 4;
    const float4 xv = *(const float4*)(X + (size_t)b * L * D + e);
    const float4 wv = *(const float4*)(W + e);
    const float4 bv = *(const float4*)(Bb + e);
    short4v o;
    o[0] = f2bf((xv.x - mu) * rstd * wv.x + bv.x);
    o[1] = f2bf((xv.y - mu) * rstd * wv.y + bv.y);
    o[2] = f2bf((xv.z - mu) * rstd * wv.z + bv.z);
    o[3] = f2bf((xv.w - mu) * rstd * wv.w + bv.w);
    *(short4v*)(Yn + (size_t)b * L * D + e) = o;
}

__global__ __launch_bounds__(256) void convert_bf(const float* __restrict__ X,
                                                  short* __restrict__ Y) {
    size_t e = (size_t)(blockIdx.x * 256 + threadIdx.x) * 4;
    const float4 v = *(const float4*)(X + e);
    short4v o = {f2bf(v.x), f2bf(v.y), f2bf(v.z), f2bf(v.w)};
    *(short4v*)(Y + e) = o;
}

// all 6 weight transposes in ONE launch. W [K][N] fp32 -> WT [N][K] bf16.
__global__ __launch_bounds__(256) void wt_transpose_all(
        const float* __restrict__ Wq, const float* __restrict__ Wk,
        const float* __restrict__ Wv, const float* __restrict__ Wo,
        const float* __restrict__ W1, const float* __restrict__ W2,
        short* __restrict__ WqT, short* __restrict__ WkvT,
        short* __restrict__ WoT, short* __restrict__ W1T,
        short* __restrict__ W2T) {
    const int id = blockIdx.x;
    const float* W; short* WT; int K, N, rel;
    if (id < 1024)      { W = Wq; WT = WqT;                    K = 1024; N = 1024; rel = id; }
    else if (id < 2048) { W = Wk; WT = WkvT;                   K = 1024; N = 1024; rel = id - 1024; }
    else if (id < 3072) { W = Wv; WT = WkvT + (size_t)D * D;   K = 1024; N = 1024; rel = id - 2048; }
    else if (id < 4096) { W = Wo; WT = WoT;                    K = 1024; N = 1024; rel = id - 3072; }
    else if (id < 8192) { W = W1; WT = W1T;                    K = 1024; N = 4096; rel = id - 4096; }
    else                { W = W2; WT = W2T;                    K = 4096; N = 1024; rel = id - 8192; }
    const int lb = (N == 4096) ? 7 : 5;          // log2(N/32)
    const int bx = rel & ((1 << lb) - 1), by = rel >> lb;

    __shared__ short tile[32][33];
    const int t = threadIdx.x;
    const int tx = t & 31, ty = t >> 5;  // 32 x 8
    const int k0 = by * 32, n0 = bx * 32;
#pragma unroll
    for (int i = 0; i < 4; ++i) {
        const int k = ty + i * 8;
        tile[k][tx] = f2bf(W[(size_t)(k0 + k) * N + n0 + tx]);
    }
    __syncthreads();
#pragma unroll
    for (int i = 0; i < 4; ++i) {
        const int n = ty + i * 8;
        WT[(size_t)(n0 + n) * K + k0 + tx] = tile[tx][n];
    }
}

// ---------------- bf16 MFMA GEMM, counted-vmcnt double-buffer ---------------
// Schedule per K-tile (BK=64): stage(t+1 -> buf^1); vmcnt(8); s_barrier;
// compute(buf); s_barrier. Final iter drains vmcnt(0) once. XOR swizzle both
// sides (measured 0 conflicts, rounds 3/5).

__device__ __forceinline__ void cv128_body(const short* __restrict__ A,
                                           const short* __restrict__ BT,
                                           const float* __restrict__ bias,
                                           const float* __restrict__ Res,
                                           void* __restrict__ Cout,
                                           int N, int Kloop, int lda, int flags,
                                           int m0, int n0,
                                           short* __restrict__ AsB,
                                           short* __restrict__ BsB) {
    const int t = threadIdx.x;
    const int wave = t >> 6, lane = t & 63;
    const int m16 = lane & 15, q4 = lane >> 4;
    const int wm = (wave >> 1) * 64, wn = (wave & 1) * 64;
    const int xorm = m16 & 7;
    const int BUFE = 128 * 64;

    float4v acc[4][4];
#pragma unroll
    for (int i = 0; i < 4; ++i)
#pragma unroll
        for (int j = 0; j < 4; ++j) acc[i][j] = (float4v){0.f, 0.f, 0.f, 0.f};

    auto stage = [&](int buf, int k0) {
        short* AsBuf = AsB + buf * BUFE;
        short* BsBuf = BsB + buf * BUFE;
#pragma unroll
        for (int p = 0; p < 4; ++p) {          // A: 128x64 bf16 = 16 KB
            const int s = p * 256 + t;
            const int row = s >> 3;
            const int col = ((s & 7) ^ (row & 7)) * 8;
            GLOAD_LDS16(A + (size_t)(m0 + row) * lda + k0 + col,
                        AsBuf + (p * 256 + wave * 64) * 8);
        }
#pragma unroll
        for (int p = 0; p < 4; ++p) {          // B: 128x64 bf16 = 16 KB
            const int s = p * 256 + t;
            const int row = s >> 3;
            const int col = ((s & 7) ^ (row & 7)) * 8;
            GLOAD_LDS16(BT + (size_t)(n0 + row) * lda + k0 + col,
                        BsBuf + (p * 256 + wave * 64) * 8);
        }
    };

    auto compute = [&](int buf) {
        const short* AsBuf = AsB + buf * BUFE;
        const short* BsBuf = BsB + buf * BUFE;
#pragma unroll
        for (int kk = 0; kk < 2; ++kk) {
            const int slot = ((kk * 4 + q4) ^ xorm) * 8;
            short8 af[4], bf[4];
#pragma unroll
            for (int mi = 0; mi < 4; ++mi)
                af[mi] = *(const short8*)&AsBuf[(wm + mi * 16 + m16) * 64 + slot];
#pragma unroll
            for (int ni = 0; ni < 4; ++ni)
                bf[ni] = *(const short8*)&BsBuf[(wn + ni * 16 + m16) * 64 + slot];
#pragma unroll
            for (int mi = 0; mi < 4; ++mi)
#pragma unroll
                for (int ni = 0; ni < 4; ++ni)
                    acc[mi][ni] = __builtin_amdgcn_mfma_f32_16x16x32_bf16(
                        af[mi], bf[ni], acc[mi][ni], 0, 0, 0);
        }
    };

    const int nt = Kloop >> 6;
    stage(0, 0);
    for (int ti = 0; ti < nt; ++ti) {
        const int cur = ti & 1;
        if (ti + 1 < nt) {
            stage(cur ^ 1, (ti + 1) << 6);
            asm volatile("s_waitcnt vmcnt(8)" ::: "memory");
        } else {
            asm volatile("s_waitcnt vmcnt(0)" ::: "memory");
        }
        __builtin_amdgcn_s_barrier();
        __builtin_amdgcn_sched_barrier(0);
        compute(cur);
        __builtin_amdgcn_s_barrier();
    }

#pragma unroll
    for (int mi = 0; mi < 4; ++mi)
#pragma unroll
        for (int ni = 0; ni < 4; ++ni) {
            const int col = n0 + wn + ni * 16 + m16;
            const float bb = bias ? bias[col] : 0.f;
#pragma unroll
            for (int r = 0; r < 4; ++r) {
                const int row = m0 + wm + mi * 16 + q4 * 4 + r;
                float v = acc[mi][ni][r] + bb;
                if (Res) v += Res[(size_t)row * N + col];
                if (flags & 1) v = fmaxf(v, 0.f);
                if (flags & 2)
                    ((short*)Cout)[(size_t)row * N + col] = f2bf(v);
                else
                    ((float*)Cout)[(size_t)row * N + col] = v;
            }
        }
}

// merged Q + KV projections: 768 blocks (3/CU).
__global__ __launch_bounds__(256) void gemm_qkv(const short* __restrict__ xb,
                                                const short* __restrict__ WqT,
                                                const float* __restrict__ bq,
                                                short* __restrict__ qb,
                                                const short* __restrict__ ynb,
                                                const short* __restrict__ WkvT,
                                                const float* __restrict__ bkv,
                                                short* __restrict__ kvb) {
    __shared__ short As[2][128 * 64];
    __shared__ short Bs[2][128 * 64];
    const int id = blockIdx.x;
    const int k = id & 7, j = id >> 3;       // 768 = 8 * 96
    const int lin = k * 96 + j;              // bijective; XCD k owns [k*96,k*96+96)
    if (lin < 256) {
        const int bx = lin & 7, by = lin >> 3;
        cv128_body(xb, WqT, bq, nullptr, qb, 1024, 1024, 1024, 2,
                   by * 128, bx * 128, &As[0][0], &Bs[0][0]);
    } else {
        const int l2 = lin - 256;
        const int bx = l2 & 15, by = l2 >> 4;
        cv128_body(ynb, WkvT, bkv, nullptr, kvb, 2048, 1024, 1024, 2,
                   by * 128, bx * 128, &As[0][0], &Bs[0][0]);
    }
}

// split-K=2 (Wo: K=1024, W2: K=4096): 512 blocks (2/CU), fp32 partials.
__global__ __launch_bounds__(256) void gemm_cv128_sk(const short* __restrict__ A,
                                                     const short* __restrict__ BT,
                                                     float* __restrict__ part,
                                                     int M, int N, int K) {
    __shared__ short As[2][128 * 64];
    __shared__ short Bs[2][128 * 64];
    const int id = blockIdx.x;
    const int k = id & 7, j = id >> 3;       // 512 = 8 * 64
    const int lin = k * 64 + j;
    const int ks = lin >> 8;                 // XCDs 0-3 -> ks 0, 4-7 -> ks 1
    const int rem = lin & 255;
    const int by = rem & 31, bx = (rem >> 5) & 7;
    const int Kc = K >> 1;
    cv128_body(A + ks * Kc, BT + ks * Kc, nullptr, nullptr,
               part + (size_t)ks * M * N, N, Kc, K, 0,
               by * 128, bx * 128, &As[0][0], &Bs[0][0]);
}

// out = part0 + part1 + bias + Res  (fp32). Final W2 epilogue.
__global__ __launch_bounds__(256) void sk_reduce(const float* __restrict__ part,
                                                 const float* __restrict__ bias,
                                                 const float* __restrict__ Res,
                                                 float* __restrict__ out,
                                                 int MN, int N) {
    const size_t e = (size_t)(blockIdx.x * 256 + threadIdx.x) * 4;
    const float4 p0 = *(const float4*)(part + e);
    const float4 p1 = *(const float4*)(part + (size_t)MN + e);
    const float4 rv = *(const float4*)(Res + e);
    const float4 bv = *(const float4*)(bias + (e & (size_t)(N - 1)));
    float4 o;
    o.x = p0.x + p1.x + rv.x + bv.x;
    o.y = p0.y + p1.y + rv.y + bv.y;
    o.z = p0.z + p1.z + rv.z + bv.z;
    o.w = p0.w + p1.w + rv.w + bv.w;
    *(float4*)(out + e) = o;
}

// Wo epilogue fused with LN2 partial reduction: writes y1 AND per-block
// (sum, sumsq) partials. Grid (2048, B): block covers one full D row.
__global__ __launch_bounds__(256) void sk_reduce_ln(const float* __restrict__ part,
                                                    const float* __restrict__ bias,
                                                    const float* __restrict__ Res,
                                                    float* __restrict__ out,
                                                    float* __restrict__ lnpart,
                                                    int MN) {
    const int b = blockIdx.y;
    const size_t e = ((size_t)b * 2048 + blockIdx.x) * 1024 + threadIdx.x * 4;
    const float4 p0 = *(const float4*)(part + e);
    const float4 p1 = *(const float4*)(part + (size_t)MN + e);
    const float4 rv = *(const float4*)(Res + e);
    const float4 bv = *(const float4*)(bias + threadIdx.x * 4);
    float4 o;
    o.x = p0.x + p1.x + rv.x + bv.x;
    o.y = p0.y + p1.y + rv.y + bv.y;
    o.z = p0.z + p1.z + rv.z + bv.z;
    o.w = p0.w + p1.w + rv.w + bv.w;
    *(float4*)(out + e) = o;
    float s = o.x + o.y + o.z + o.w;
    float ss = o.x * o.x + o.y * o.y + o.z * o.z + o.w * o.w;
    __shared__ float sh0[256], sh1[256];
    sh0[threadIdx.x] = s; sh1[threadIdx.x] = ss;
    __syncthreads();
    for (int off = 128; off; off >>= 1) {
        if (threadIdx.x < off) {
            sh0[threadIdx.x] += sh0[threadIdx.x + off];
            sh1[threadIdx.x] += sh1[threadIdx.x + off];
        }
        __syncthreads();
    }
    if (threadIdx.x == 0) {
        lnpart[((size_t)b * 2048 + blockIdx.x) * 2 + 0] = sh0[0];
        lnpart[((size_t)b * 2048 + blockIdx.x) * 2 + 1] = sh1[0];
    }
}

// 256x256 tile, 8 waves (2M x 4N), wave tile 128x64 (W1).
__global__ __launch_bounds__(512) void gemm_cv256(const short* __restrict__ A,
                                                  const short* __restrict__ BT,
                                                  const float* __restrict__ bias,
                                                  const float* __restrict__ Res,
                                                  void* __restrict__ Cout,
                                                  int M, int N, int K, int flags) {
    __shared__ short As[2][256 * 64];
    __shared__ short Bs[2][256 * 64];
    const int t = threadIdx.x;
    const int wave = t >> 6, lane = t & 63;
    const int m16 = lane & 15, q4 = lane >> 4;
    int bx, by;
    xcd_remap(bx, by);
    const int m0 = by * 256, n0 = bx * 256;
    const int wm = (wave >> 2) * 128, wn = (wave & 3) * 64;
    const int xorm = m16 & 7;

    float4v acc[8][4];
#pragma unroll
    for (int i = 0; i < 8; ++i)
#pragma unroll
        for (int j = 0; j < 4; ++j) acc[i][j] = (float4v){0.f, 0.f, 0.f, 0.f};

    auto stage = [&](int buf, int k0) {
#pragma unroll
        for (int p = 0; p < 4; ++p) {          // A: 256x64 bf16 = 32 KB
            const int s = p * 512 + t;
            const int row = s >> 3;
            const int col = ((s & 7) ^ (row & 7)) * 8;
            short* lds = &As[buf][(p * 512 + wave * 64) * 8];
            GLOAD_LDS16(A + (size_t)(m0 + row) * K + k0 + col, lds);
        }
#pragma unroll
        for (int p = 0; p < 4; ++p) {          // B: 256x64 bf16 = 32 KB
            const int s = p * 512 + t;
            const int row = s >> 3;
            const int col = ((s & 7) ^ (row & 7)) * 8;
            short* lds = &Bs[buf][(p * 512 + wave * 64) * 8];
            GLOAD_LDS16(BT + (size_t)(n0 + row) * K + k0 + col, lds);
        }
    };

    auto compute = [&](int buf) {
#pragma unroll
        for (int kk = 0; kk < 2; ++kk) {
            const int slot = ((kk * 4 + q4) ^ xorm) * 8;
            short8 af[8], bf[4];
#pragma unroll
            for (int mi = 0; mi < 8; ++mi)
                af[mi] = *(const short8*)&As[buf][(wm + mi * 16 + m16) * 64 + slot];
#pragma unroll
            for (int ni = 0; ni < 4; ++ni)
                bf[ni] = *(const short8*)&Bs[buf][(wn + ni * 16 + m16) * 64 + slot];
#pragma unroll
            for (int mi = 0; mi < 8; ++mi)
#pragma unroll
                for (int ni = 0; ni < 4; ++ni)
                    acc[mi][ni] = __builtin_amdgcn_mfma_f32_16x16x32_bf16(
                        af[mi], bf[ni], acc[mi][ni], 0, 0, 0);
        }
    };

    const int nt = K >> 6;
    stage(0, 0);
    for (int ti = 0; ti < nt; ++ti) {
        const int cur = ti & 1;
        if (ti + 1 < nt) {
            stage(cur ^ 1, (ti + 1) << 6);
            asm volatile("s_waitcnt vmcnt(8)" ::: "memory");
        } else {
            asm volatile("s_waitcnt vmcnt(0)" ::: "memory");
        }
        __builtin_amdgcn_s_barrier();
        __builtin_amdgcn_sched_barrier(0);
        compute(cur);
        __builtin_amdgcn_s_barrier();
    }

#pragma unroll
    for (int mi = 0; mi < 8; ++mi)
#pragma unroll
        for (int ni = 0; ni < 4; ++ni) {
            const int col = n0 + wn + ni * 16 + m16;
            const float bb = bias[col];
#pragma unroll
            for (int r = 0; r < 4; ++r) {
                const int row = m0 + wm + mi * 16 + q4 * 4 + r;
                float v = acc[mi][ni][r] + bb;
                if (Res) v += Res[(size_t)row * N + col];
                if (flags & 1) v = fmaxf(v, 0.f);
                if (flags & 2)
                    ((short*)Cout)[(size_t)row * N + col] = f2bf(v);
                else
                    ((float*)Cout)[(size_t)row * N + col] = v;
            }
        }
}

// ---------------- V transpose + tile sums (fused) ---------------------------
// tril-ZERO semantics: p=exp(0)=1 for all j>i, so
//   out[i] = (sum_{j<=i} e^{s_j} v_j + sum_{j>i} v_j) / (sum_{j<=i} e^{s_j} + (L-1-i))
// vtb ALIASES hb[0:8MB] (dead until W1; W1 runs after attention completes).

#define ASTR 72
#define SKV (2 * D)

__global__ __launch_bounds__(256) void v_transpose(const short* __restrict__ KVg,
                                                   short* __restrict__ VT,
                                                   float* __restrict__ Vtile) {
    __shared__ short tile[64 * ASTR];
    __shared__ float sh[4][64];
    const int t = threadIdx.x;
    const int bh = blockIdx.x >> 5;          // 32 j-tiles of 64 per bh
    const int jt = blockIdx.x & 31;
    const int b = bh >> 4, h = bh & (H - 1);
    const size_t baseV = (size_t)b * L * SKV + (size_t)h * DK + D;
    const int j0 = jt * 64;
    const int sj = t >> 3, sd8 = (t & 7) * 8, sm = t & 7;
#pragma unroll
    for (int rep = 0; rep < 2; ++rep) {
        const int j = rep * 32 + sj;
        const short8 vv = *(const short8*)(KVg + baseV + (size_t)(j0 + j) * SKV + sd8);
        const int jsw = ((((j >> 3) ^ sm) << 3) | (j & 7));
#pragma unroll
        for (int i = 0; i < 8; ++i) tile[(sd8 + i) * ASTR + jsw] = vv[i];
    }
    __syncthreads();
#pragma unroll
    for (int rep = 0; rep < 2; ++rep) {
        const int s = rep * 256 + t;
        const int d = s >> 3, c = s & 7;
        const short8 vv = *(const short8*)&tile[d * ASTR + ((c ^ (d >> 3)) << 3)];
        *(short8*)(VT + ((size_t)bh * DK + d) * L + j0 + c * 8) = vv;
    }
    // fused tile sum over j (row d holds a permutation of its j's)
    {
        const int d = t & 63, g = t >> 6;
        float s = 0.f;
#pragma unroll
        for (int c = 0; c < 16; ++c) s += bf2f(tile[d * ASTR + g * 16 + c]);
        sh[g][d] = s;
        __syncthreads();
        if (t < 64)
            Vtile[((size_t)bh * 32 + jt) * 64 + t] =
                sh[0][t] + sh[1][t] + sh[2][t] + sh[3][t];
    }
}

__global__ __launch_bounds__(64) void v_suffix(const float* __restrict__ Vtile,
                                               float* __restrict__ Vsuf) {
    const int bh = blockIdx.x;
    const int d = threadIdx.x;
    float s = 0.f;
    Vsuf[((size_t)bh * 33 + 32) * 64 + d] = 0.f;
    for (int kt = 31; kt >= 0; --kt) {
        s += Vtile[((size_t)bh * 32 + kt) * 64 + d];
        Vsuf[((size_t)bh * 33 + kt) * 64 + d] = s;
    }
}

// ---------------- MFMA flash attention v5 (round-8 proven core) -------------
// UNIFORM paired blocks (qt=u then 31-u: 33 tiles/block). Pure global_load_lds
// staging (K from kvb, V^T from vtb) with source-XOR swizzle; 2-deep counted
// vmcnt schedule. Masked tail via PRECOMPUTED vsuf (one load per f — the
// round-10 inline-suffix loop was a serial-latency chain, −22 µs).

__global__ __launch_bounds__(256) void attn_mfma(const short* __restrict__ Qg,
                                                 const short* __restrict__ KVg,
                                                 const short* __restrict__ VTg,
                                                 const float* __restrict__ Vsuf,
                                                 short* __restrict__ O) {
    __shared__ alignas(16) short Kb[2][64 * 64];  // Kb[buf][j][d], XOR-swz
    __shared__ alignas(16) short Vt[2][64 * 64];  // Vt[buf][d][j], XOR-swz
    __shared__ alignas(16) short Pb[64 * ASTR];   // Pb[i][j], swizzled

    const int t = threadIdx.x;
    const int wave = t >> 6;
    const int lane = t & 63;
    const int m16 = lane & 15;
    const int q4 = lane >> 4;

    const int u = blockIdx.x & 15;          // pair id: qt = u, then 31-u
    const int bh = blockIdx.x >> 4;
    const int h = bh & (H - 1);
    const int b = bh >> 4;
    const size_t baseQ = (size_t)b * L * D + (size_t)h * DK;
    const size_t baseK = (size_t)b * L * SKV + (size_t)h * DK;
    const size_t baseVT = (size_t)bh * DK * L;  // vtb [d][j], row stride L

    const int irow = wave * 16 + m16;   // local q row (A-frag row for PV)
    const int ig = irow >> 3;
    const int xorm = m16 & 7;

    auto stage = [&](int buf, int kt0) {
#pragma unroll
        for (int rep = 0; rep < 2; ++rep) {   // K tile: 64 j x 64 d = 8 KB
            const int s = rep * 256 + t;
            const int j = s >> 3;
            const int c = (s & 7) ^ (j & 7);
            GLOAD_LDS16(KVg + baseK + (size_t)(kt0 + j) * SKV + c * 8,
                        &Kb[buf][(rep * 256 + wave * 64) * 8]);
        }
#pragma unroll
        for (int rep = 0; rep < 2; ++rep) {   // V^T tile: 64 d x 64 j = 8 KB
            const int s = rep * 256 + t;
            const int d = s >> 3;
            const int c = (s & 7) ^ (d & 7);
            GLOAD_LDS16(VTg + baseVT + (size_t)d * L + kt0 + c * 8,
                        &Vt[buf][(rep * 256 + wave * 64) * 8]);
        }
    };

#pragma unroll
    for (int pq = 0; pq < 2; ++pq) {
        const int qt = pq ? (31 - u) : u;
        const int q0 = qt * 64;
        const int rowA = q0 + wave * 16 + m16;

        short8 qf[2];
#pragma unroll
        for (int kc = 0; kc < 2; ++kc)
            qf[kc] = *(const short8*)(Qg + baseQ + (size_t)rowA * D + kc * 32 + q4 * 8);

        float lsum = 0.f;
        float4v acc[4];
#pragma unroll
        for (int f = 0; f < 4; ++f) acc[f] = (float4v){0.f, 0.f, 0.f, 0.f};

        stage(0, 0);
        for (int kt = 0; kt <= qt; ++kt) {
            const int cur = kt & 1;
            if (kt < qt) {
                stage(cur ^ 1, (kt + 1) * 64);
                asm volatile("s_waitcnt vmcnt(4)" ::: "memory");
            } else {
                asm volatile("s_waitcnt vmcnt(0)" ::: "memory");
            }
            __builtin_amdgcn_s_barrier();
            __builtin_amdgcn_sched_barrier(0);

            const short* KbC = &Kb[cur][0];
            const short* VtC = &Vt[cur][0];
            const bool diag = (kt == qt);

            // S^T block per f: rows k = f*16 + q4*4 + r, col q = m16
#pragma unroll
            for (int f = 0; f < 4; ++f) {
                const int krow = f * 16 + m16;
                const short8 kf0 = *(const short8*)&KbC[krow * 64 + ((q4 ^ xorm) << 3)];
                const short8 kf1 = *(const short8*)&KbC[krow * 64 + (((4 + q4) ^ xorm) << 3)];
                float4v sv = {0.f, 0.f, 0.f, 0.f};
                sv = __builtin_amdgcn_mfma_f32_16x16x32_bf16(kf0, qf[0], sv, 0, 0, 0);
                sv = __builtin_amdgcn_mfma_f32_16x16x32_bf16(kf1, qf[1], sv, 0, 0, 0);

                float pv[4];
                if (diag) {
#pragma unroll
                    for (int r = 0; r < 4; ++r) {
                        const int jl = f * 16 + q4 * 4 + r;
                        pv[r] = (jl <= irow) ? __expf(sv[r] * 0.125f) : 1.0f;
                    }
                } else {
#pragma unroll
                    for (int r = 0; r < 4; ++r) pv[r] = __expf(sv[r] * 0.125f);
                }
                lsum += pv[0] + pv[1] + pv[2] + pv[3];

                // 4 consecutive k -> one b64 write into swizzled Pb[i][j]
                short4v s4;
                s4[0] = f2bf(pv[0]); s4[1] = f2bf(pv[1]);
                s4[2] = f2bf(pv[2]); s4[3] = f2bf(pv[3]);
                const int jb = f * 2 + (q4 >> 1);
                *(short4v*)&Pb[irow * ASTR + (((jb ^ ig) << 3) | ((q4 & 1) << 2))] = s4;
            }

            // PV (per-wave band of Pb, no extra barrier)
#pragma unroll
            for (int kc = 0; kc < 2; ++kc) {
                const short8 pf = *(const short8*)&Pb[irow * ASTR + (((kc * 4 + q4) ^ ig) << 3)];
#pragma unroll
                for (int f = 0; f < 4; ++f) {
                    const int d = f * 16 + m16;
                    const short8 vf = *(const short8*)&VtC[d * 64 + (((kc * 4 + q4) ^ xorm) << 3)];
                    acc[f] = __builtin_amdgcn_mfma_f32_16x16x32_bf16(pf, vf, acc[f], 0, 0, 0);
                }
            }
            __builtin_amdgcn_s_barrier();
        }

        // denom: reduce lsum over q4 axis, add masked count, broadcast per row
        float s = lsum;
        s += __shfl_xor(s, 16);
        s += __shfl_xor(s, 32);
        s += (float)(L - (qt + 1) * 64);
        const float inv = 1.0f / s;
        float invr[4];
#pragma unroll
        for (int r = 0; r < 4; ++r) invr[r] = __shfl(inv, q4 * 4 + r);

        const float* vs = Vsuf + ((size_t)bh * 33 + qt + 1) * 64;
#pragma unroll
        for (int f = 0; f < 4; ++f) {
            const float vadd = vs[f * 16 + m16];
#pragma unroll
            for (int r = 0; r < 4; ++r) {
                const int i = q0 + wave * 16 + q4 * 4 + r;
                O[baseQ + (size_t)i * D + f * 16 + m16] = f2bf((acc[f][r] + vadd) * invr[r]);
            }
        }
    }
}

// ---------------- launch ----------------------------------------------------

extern "C" void kernel_launch(void* const* d_in, const int* in_sizes, int n_in,
                              void* d_out, int out_size, void* d_ws, size_t ws_size,
                              hipStream_t stream) {
    const float* x    = (const float*)d_in[0];
    const float* y    = (const float*)d_in[1];
    const float* Wq   = (const float*)d_in[2];
    const float* bq   = (const float*)d_in[3];
    const float* Wk   = (const float*)d_in[4];
    const float* bk   = (const float*)d_in[5];
    const float* Wv   = (const float*)d_in[6];
    const float* bv   = (const float*)d_in[7];
    const float* Wo   = (const float*)d_in[8];
    const float* bo   = (const float*)d_in[9];
    const float* W1   = (const float*)d_in[10];
    const float* b1   = (const float*)d_in[11];
    const float* W2   = (const float*)d_in[12];
    const float* b2   = (const float*)d_in[13];
    const float* ln1w = (const float*)d_in[14];
    const float* ln1b = (const float*)d_in[15];
    const float* ln2w = (const float*)d_in[16];
    const float* ln2b = (const float*)d_in[17];
    float* out = (float*)d_out;

    const size_t F = (size_t)B * L * D;      // 4,194,304
    char* p = (char*)d_ws;
    short* xb    = (short*)p; p += F * 2;
    short* ynb   = (short*)p; p += F * 2;
    short* qb    = (short*)p; p += F * 2;
    short* kvb   = (short*)p; p += 2 * F * 2;     // [M][2048]: k | v
    short* aob   = (short*)p; p += F * 2;
    short* y1nb  = (short*)p; p += F * 2;
    short* hb    = (short*)p; p += (size_t)B * L * DFF * 2;
    float* y1    = (float*)p; p += F * 4;
    short* WqT   = (short*)p; p += (size_t)D * D * 2;
    short* WkvT  = (short*)p; p += (size_t)D * 2 * D * 2;  // [2048][1024]
    short* WoT   = (short*)p; p += (size_t)D * D * 2;
    short* W1T   = (short*)p; p += (size_t)D * DFF * 2;
    short* W2T   = (short*)p; p += (size_t)D * DFF * 2;
    float* biaskv= (float*)p; p += 2 * D * 4;
    float* vtile = (float*)p; p += (size_t)B * H * 32 * DK * 4;
    float* vsuf  = (float*)p; p += (size_t)B * H * 33 * DK * 4;
    float* part  = (float*)p; p += (size_t)B * 2048 * 2 * 4;
    float* stats = (float*)p;

    // vtb (V^T, 8 MB) aliases hb[0:8MB]: hb dead until W1 (runs post-attn).
    short* vtb = hb;
    // Wo split-K partials (32 MB) also in hb (written after attn consumed vtb).
    float* skpartWo = (float*)hb;
    // W2 split-K partials reuse dead qb|kvb|aob (32 MB contiguous).
    float* skpart = (float*)qb;

    const int M = B * L;  // 4096

    // all weight transposes in one launch
    wt_transpose_all<<<dim3(12288), 256, 0, stream>>>(Wq, Wk, Wv, Wo, W1, W2,
                                                      WqT, WkvT, WoT, W1T, W2T);
    hipMemcpyAsync(biaskv,     bk, D * sizeof(float), hipMemcpyDeviceToDevice, stream);
    hipMemcpyAsync(biaskv + D, bv, D * sizeof(float), hipMemcpyDeviceToDevice, stream);

    // x -> bf16
    convert_bf<<<dim3(F / 1024), 256, 0, stream>>>(x, xb);

    // LN1(y) -> ynb (bf16)
    red_partial<<<dim3(256, B), 256, 0, stream>>>(y, part);
    red_final<<<dim3(B), 256, 0, stream>>>(part, stats, 256);
    ln_apply_bf<<<dim3(L * D / 1024, B), 256, 0, stream>>>(y, ln1w, ln1b, stats, ynb);

    // q = x@Wq and kv = ynb@[Wk|Wv], merged: 768 blocks = 3/CU
    gemm_qkv<<<dim3(768), 256, 0, stream>>>(xb, WqT, bq, qb, ynb, WkvT, biaskv, kvb);

    // V^T + tile sums (fused), then suffix (precomputed: one load per f in attn)
    v_transpose<<<dim3(B * H * 32), 256, 0, stream>>>(kvb, vtb, vtile);
    v_suffix<<<dim3(B * H), 64, 0, stream>>>(vtile, vsuf);

    // attention -> aob (bf16): uniform paired blocks, gload_lds staging
    attn_mfma<<<dim3(B * H * 16), 256, 0, stream>>>(qb, kvb, vtb, vsuf, aob);

    // y1 = y + attn@Wo + bo (fp32): split-K=2 + reduce FUSED with LN2 partials
    gemm_cv128_sk<<<dim3(512), 256, 0, stream>>>(aob, WoT, skpartWo, M, D, D);
    sk_reduce_ln<<<dim3(2048, B), 256, 0, stream>>>(skpartWo, bo, y, y1, part, M * D);
    red_final<<<dim3(B), 256, 0, stream>>>(part, stats, 2048);
    ln_apply_bf<<<dim3(L * D / 1024, B), 256, 0, stream>>>(y1, ln2w, ln2b, stats, y1nb);

    // h = relu(y1n@W1 + b1) (bf16) -- 256^2 8-wave counted-vmcnt kernel
    // (first write to hb; clobbers vtb / Wo partials, both consumed)
    gemm_cv256<<<dim3(DFF / 256, M / 256), 512, 0, stream>>>(y1nb, W1T, b1, nullptr, hb, M, DFF, D, 3);

    // out = y1 + h@W2 + b2 (fp32): split-K=2 partials + fused reduce
    gemm_cv128_sk<<<dim3(512), 256, 0, stream>>>(hb, W2T, skpart, M, D, DFF);
    sk_reduce<<<dim3(M * D / 1024), 256, 0, stream>>>(skpart, b2, y1, out, M * D, D);
}